// Round 1
// baseline (871.096 us; speedup 1.0000x reference)
//
#include <hip/hip_runtime.h>

// FastHelgasonMLP: out[b,t,o] = sum_i x[b,t,i] * W[o,i], W = U diag(S) V^T
// Factored: t = x @ (V*S)  [16384,1024], out = t @ U^T  [16384,4096]
// bf16 MFMA 16x16x32, fp32 accumulate.
// R1 change: GEMM staging via __builtin_amdgcn_global_load_lds width=16
// (m97 structure: linear LDS [128][32], 2 barriers/K-step, async DMA staging).

typedef __bf16 bf16;
typedef __bf16 bf16x4 __attribute__((ext_vector_type(4)));
typedef __bf16 bf16x8 __attribute__((ext_vector_type(8)));
typedef float  f32x4  __attribute__((ext_vector_type(4)));

#define M_DIM   16384   // B*T
#define IN_DIM  4096
#define OUT_DIM 4096
#define RK_DIM  1024

// ---------------------------------------------------------------------------
// Prep: blocks [0, xblocks)          : cast x fp32 -> bf16          (2048 f4/blk)
//       blocks [xblocks, +512)       : cast U fp32 -> bf16          (2048 f4/blk)
//       blocks [xblocks+512, +1024)  : VsT[r][i] = V[i][r]*S[r] bf16 (64x64 tile)
// ---------------------------------------------------------------------------
__global__ __launch_bounds__(256)
void prep_kernel(const float* __restrict__ x, const float* __restrict__ U,
                 const float* __restrict__ S, const float* __restrict__ V,
                 bf16* __restrict__ xb, bf16* __restrict__ Ub,
                 bf16* __restrict__ VsT, int xblocks)
{
    __shared__ float tile[64][68];   // +4 pad: conflict-free enough, only V path uses
    const int b = blockIdx.x;
    const int tid = threadIdx.x;

    if (b < xblocks) {
        const float4* xin = (const float4*)x;
        size_t base = (size_t)b * 2048 + tid;
        #pragma unroll
        for (int i = 0; i < 8; ++i) {
            float4 v = xin[base + (size_t)i * 256];
            bf16x4 o = { (bf16)v.x, (bf16)v.y, (bf16)v.z, (bf16)v.w };
            *(bf16x4*)&xb[(base + (size_t)i * 256) * 4] = o;
        }
    } else if (b < xblocks + 512) {
        const float4* uin = (const float4*)U;
        size_t base = (size_t)(b - xblocks) * 2048 + tid;
        #pragma unroll
        for (int i = 0; i < 8; ++i) {
            float4 v = uin[base + (size_t)i * 256];
            bf16x4 o = { (bf16)v.x, (bf16)v.y, (bf16)v.z, (bf16)v.w };
            *(bf16x4*)&Ub[(base + (size_t)i * 256) * 4] = o;
        }
    } else {
        const int vb   = b - (xblocks + 512);
        const int rblk = vb & 15;        // 1024/64 = 16 tiles along rank
        const int iblk = vb >> 4;        // 4096/64 = 64 tiles along in
        const int r0 = rblk * 64, i0 = iblk * 64;

        const int tr  = tid >> 4;        // 0..15
        const int tc4 = (tid & 15) * 4;  // 0..60
        #pragma unroll
        for (int j = 0; j < 4; ++j) {
            float4 v = *(const float4*)&V[(size_t)(i0 + tr + j * 16) * RK_DIM + r0 + tc4];
            tile[tr + j * 16][tc4 + 0] = v.x;
            tile[tr + j * 16][tc4 + 1] = v.y;
            tile[tr + j * 16][tc4 + 2] = v.z;
            tile[tr + j * 16][tc4 + 3] = v.w;
        }
        __syncthreads();
        const int rr  = tid >> 2;        // 0..63 (local rank row)
        const int ic0 = (tid & 3) * 16;  // 0..48 (local in col base)
        const float s = S[r0 + rr];
        #pragma unroll
        for (int j = 0; j < 4; ++j) {
            bf16x4 o;
            #pragma unroll
            for (int q = 0; q < 4; ++q)
                o[q] = (bf16)(tile[ic0 + j * 4 + q][rr] * s);
            *(bf16x4*)&VsT[(size_t)(r0 + rr) * IN_DIM + i0 + ic0 + j * 4] = o;
        }
    }
}

// ---------------------------------------------------------------------------
// Async global->LDS staging helper (16B per lane; LDS dest = wave-uniform
// base + lane*16, so LDS layout must be linear in lane order — no padding).
// ---------------------------------------------------------------------------
__device__ __forceinline__ void gload16(const bf16* g, bf16* l)
{
    __builtin_amdgcn_global_load_lds(
        (const __attribute__((address_space(1))) void*)g,
        (__attribute__((address_space(3))) void*)l,
        16, 0, 0);
}

// ---------------------------------------------------------------------------
// gemm_bt_async: C[M,N] = A[M,K] * B[N,K]^T, bf16 inputs, fp32 accumulate.
// Block = 256 thr (4 waves 2x2), tile 128x128, BK=32, MFMA f32_16x16x32_bf16.
// LDS linear [128][32] (64B rows); staging via global_load_lds_dwordx4:
// each wave issues 2 chunks of 1024B per operand tile (4 waves x 2 x 1024B
// = 8192B = 128x32 bf16). m97 structure — known ~874-912 TF at 4096^3.
// ---------------------------------------------------------------------------
template <typename CT>
__global__ __launch_bounds__(256)
void gemm_bt_async(const bf16* __restrict__ A, const bf16* __restrict__ B,
                   CT* __restrict__ C, int M, int N, int K)
{
    __shared__ bf16 As[128][32];
    __shared__ bf16 Bs[128][32];

    const int tid  = threadIdx.x;
    const int lane = tid & 63;
    const int wave = tid >> 6;
    const int wrow = wave >> 1;      // 0..1
    const int wcol = wave & 1;       // 0..1
    const int n0 = blockIdx.x * 128;
    const int m0 = blockIdx.y * 128;

    f32x4 acc[4][4];
    #pragma unroll
    for (int mi = 0; mi < 4; ++mi)
        #pragma unroll
        for (int ni = 0; ni < 4; ++ni)
            acc[mi][ni] = (f32x4){0.f, 0.f, 0.f, 0.f};

    const int fr = lane & 15;            // fragment row (m or n)
    const int kq = (lane >> 4) * 8;      // fragment k base

    // staging geometry: chunk = i*4+wave covers LDS bytes [chunk*1024, +1024)
    // lane l covers element chunk*512 + l*8 -> row = chunk*16 + (l>>2),
    // k = (l&3)*8. Global source is per-lane; LDS base is wave-uniform.
    const int srow = lane >> 2;          // 0..15 (row within chunk)
    const int skc  = (lane & 3) * 8;     // k offset 0/8/16/24

    for (int kk = 0; kk < K; kk += 32) {
        __syncthreads();                 // prior iter's LDS reads done
        #pragma unroll
        for (int i = 0; i < 2; ++i) {
            const int chunk = i * 4 + wave;
            const int row   = chunk * 16 + srow;
            gload16(&A[(size_t)(m0 + row) * K + kk + skc], &As[0][0] + chunk * 512);
            gload16(&B[(size_t)(n0 + row) * K + kk + skc], &Bs[0][0] + chunk * 512);
        }
        __syncthreads();                 // vmcnt(0) drained by compiler here

        // ---- fragments: A[m=lane&15][k=(lane>>4)*8+j], B^T same addressing ----
        bf16x8 af[4], bfg[4];
        #pragma unroll
        for (int i = 0; i < 4; ++i) {
            af[i]  = *(const bf16x8*)&As[wrow * 64 + i * 16 + fr][kq];
            bfg[i] = *(const bf16x8*)&Bs[wcol * 64 + i * 16 + fr][kq];
        }
        #pragma unroll
        for (int mi = 0; mi < 4; ++mi)
            #pragma unroll
            for (int ni = 0; ni < 4; ++ni)
                acc[mi][ni] = __builtin_amdgcn_mfma_f32_16x16x32_bf16(
                    af[mi], bfg[ni], acc[mi][ni], 0, 0, 0);
    }

    // ---- epilogue: C/D layout col=lane&15, row=(lane>>4)*4+reg (m89/m91) ----
    const int ccol  = n0 + wcol * 64 + fr;
    const int crow0 = m0 + wrow * 64 + (lane >> 4) * 4;
    #pragma unroll
    for (int mi = 0; mi < 4; ++mi)
        #pragma unroll
        for (int ni = 0; ni < 4; ++ni)
            #pragma unroll
            for (int r = 0; r < 4; ++r)
                C[(size_t)(crow0 + mi * 16 + r) * N + ccol + ni * 16] =
                    (CT)acc[mi][ni][r];
}

// ---------------------------------------------------------------------------
// Fallback GEMM (fp32 A, register staging) — only used when the workspace is
// too small to hold the bf16 copy of x. Unchanged from the verified baseline.
// ---------------------------------------------------------------------------
__global__ __launch_bounds__(256)
void gemm_bt_f32a(const float* __restrict__ A, const bf16* __restrict__ B,
                  bf16* __restrict__ C, int M, int N, int K)
{
    __shared__ bf16 As[128][40];
    __shared__ bf16 Bs[128][40];

    const int tid  = threadIdx.x;
    const int lane = tid & 63;
    const int wave = tid >> 6;
    const int wrow = wave >> 1;
    const int wcol = wave & 1;
    const int n0 = blockIdx.x * 128;
    const int m0 = blockIdx.y * 128;

    f32x4 acc[4][4];
    #pragma unroll
    for (int mi = 0; mi < 4; ++mi)
        #pragma unroll
        for (int ni = 0; ni < 4; ++ni)
            acc[mi][ni] = (f32x4){0.f, 0.f, 0.f, 0.f};

    const int fr = lane & 15;
    const int kq = (lane >> 4) * 8;

    for (int kk = 0; kk < K; kk += 32) {
        __syncthreads();
        #pragma unroll
        for (int i = 0; i < 4; ++i) {
            int c = tid + i * 256;
            int row = c >> 3, kc = (c & 7) * 4;
            float4 v = *(const float4*)&A[(size_t)(m0 + row) * K + kk + kc];
            bf16x4 o = { (bf16)v.x, (bf16)v.y, (bf16)v.z, (bf16)v.w };
            *(bf16x4*)&As[row][kc] = o;
        }
        #pragma unroll
        for (int i = 0; i < 2; ++i) {
            int c = tid + i * 256;
            int row = c >> 2, kc = (c & 3) * 8;
            *(bf16x8*)&Bs[row][kc] = *(const bf16x8*)&B[(size_t)(n0 + row) * K + kk + kc];
        }
        __syncthreads();

        bf16x8 af[4], bfg[4];
        #pragma unroll
        for (int i = 0; i < 4; ++i) {
            af[i]  = *(const bf16x8*)&As[wrow * 64 + i * 16 + fr][kq];
            bfg[i] = *(const bf16x8*)&Bs[wcol * 64 + i * 16 + fr][kq];
        }
        #pragma unroll
        for (int mi = 0; mi < 4; ++mi)
            #pragma unroll
            for (int ni = 0; ni < 4; ++ni)
                acc[mi][ni] = __builtin_amdgcn_mfma_f32_16x16x32_bf16(
                    af[mi], bfg[ni], acc[mi][ni], 0, 0, 0);
    }

    const int ccol  = n0 + wcol * 64 + fr;
    const int crow0 = m0 + wrow * 64 + (lane >> 4) * 4;
    #pragma unroll
    for (int mi = 0; mi < 4; ++mi)
        #pragma unroll
        for (int ni = 0; ni < 4; ++ni)
            #pragma unroll
            for (int r = 0; r < 4; ++r)
                C[(size_t)(crow0 + mi * 16 + r) * N + ccol + ni * 16] =
                    (bf16)acc[mi][ni][r];
}

// ---------------------------------------------------------------------------
extern "C" void kernel_launch(void* const* d_in, const int* in_sizes, int n_in,
                              void* d_out, int out_size, void* d_ws, size_t ws_size,
                              hipStream_t stream)
{
    const float* x = (const float*)d_in[0];   // [4,4096,4096]
    const float* U = (const float*)d_in[1];   // [4096,1024]
    const float* S = (const float*)d_in[2];   // [1024]
    const float* V = (const float*)d_in[3];   // [4096,1024]
    float* out = (float*)d_out;               // [4,4096,4096]

    const size_t SZ_XB  = (size_t)M_DIM * IN_DIM * 2;   // 128 MiB
    const size_t SZ_UB  = (size_t)OUT_DIM * RK_DIM * 2; //   8 MiB
    const size_t SZ_VST = (size_t)RK_DIM * IN_DIM * 2;  //   8 MiB
    const size_t SZ_T   = (size_t)M_DIM * RK_DIM * 2;   //  32 MiB

    char* p = (char*)d_ws;
    const bool full = ws_size >= SZ_XB + SZ_UB + SZ_VST + SZ_T;
    bf16* xb = nullptr;
    if (full) { xb = (bf16*)p; p += SZ_XB; }
    bf16* Ub  = (bf16*)p; p += SZ_UB;
    bf16* VsT = (bf16*)p; p += SZ_VST;
    bf16* t   = (bf16*)p;

    const int xblocks = full ? 8192 : 0;
    prep_kernel<<<xblocks + 512 + 1024, 256, 0, stream>>>(
        x, U, S, V, full ? xb : Ub, Ub, VsT, xblocks);

    // GEMM1: t[M, RK] = xb[M, IN] * VsT[RK, IN]^T
    if (full)
        gemm_bt_async<bf16><<<dim3(RK_DIM / 128, M_DIM / 128), 256, 0, stream>>>(
            xb, VsT, t, M_DIM, RK_DIM, IN_DIM);
    else
        gemm_bt_f32a<<<dim3(RK_DIM / 128, M_DIM / 128), 256, 0, stream>>>(
            x, VsT, t, M_DIM, RK_DIM, IN_DIM);

    // GEMM2: out[M, OUT] = t[M, RK] * Ub[OUT, RK]^T
    gemm_bt_async<float><<<dim3(OUT_DIM / 128, M_DIM / 128), 256, 0, stream>>>(
        t, Ub, out, M_DIM, OUT_DIM, RK_DIM);
}

// Round 2
// 706.402 us; speedup vs baseline: 1.2331x; 1.2331x over previous
//
#include <hip/hip_runtime.h>

// FastHelgasonMLP: out = x @ (U diag(S) V^T)^T, factored:
//   t[16384,1024] = xb @ VsT^T ;  out[16384,4096] = t @ Ub^T
// R2: 256x256 8-phase GEMM (T2 LDS-swizzle + T3/T4 counted-vmcnt pipeline +
// T5 setprio), per the verified m201 template. bf16 MFMA 16x16x32, fp32 acc.

typedef __bf16 bf16;
typedef __bf16 bf16x4 __attribute__((ext_vector_type(4)));
typedef __bf16 bf16x8 __attribute__((ext_vector_type(8)));
typedef float  f32x4  __attribute__((ext_vector_type(4)));

#define M_DIM   16384
#define IN_DIM  4096
#define OUT_DIM 4096
#define RK_DIM  1024

// ---------------------------------------------------------------------------
// Prep (unchanged): cast x->bf16, U->bf16, build VsT[r][i] = V[i][r]*S[r].
// ---------------------------------------------------------------------------
__global__ __launch_bounds__(256)
void prep_kernel(const float* __restrict__ x, const float* __restrict__ U,
                 const float* __restrict__ S, const float* __restrict__ V,
                 bf16* __restrict__ xb, bf16* __restrict__ Ub,
                 bf16* __restrict__ VsT, int xblocks)
{
    __shared__ float tile[64][68];
    const int b = blockIdx.x;
    const int tid = threadIdx.x;

    if (b < xblocks) {
        const float4* xin = (const float4*)x;
        size_t base = (size_t)b * 2048 + tid;
        #pragma unroll
        for (int i = 0; i < 8; ++i) {
            float4 v = xin[base + (size_t)i * 256];
            bf16x4 o = { (bf16)v.x, (bf16)v.y, (bf16)v.z, (bf16)v.w };
            *(bf16x4*)&xb[(base + (size_t)i * 256) * 4] = o;
        }
    } else if (b < xblocks + 512) {
        const float4* uin = (const float4*)U;
        size_t base = (size_t)(b - xblocks) * 2048 + tid;
        #pragma unroll
        for (int i = 0; i < 8; ++i) {
            float4 v = uin[base + (size_t)i * 256];
            bf16x4 o = { (bf16)v.x, (bf16)v.y, (bf16)v.z, (bf16)v.w };
            *(bf16x4*)&Ub[(base + (size_t)i * 256) * 4] = o;
        }
    } else {
        const int vb   = b - (xblocks + 512);
        const int rblk = vb & 15;
        const int iblk = vb >> 4;
        const int r0 = rblk * 64, i0 = iblk * 64;

        const int tr  = tid >> 4;
        const int tc4 = (tid & 15) * 4;
        #pragma unroll
        for (int j = 0; j < 4; ++j) {
            float4 v = *(const float4*)&V[(size_t)(i0 + tr + j * 16) * RK_DIM + r0 + tc4];
            tile[tr + j * 16][tc4 + 0] = v.x;
            tile[tr + j * 16][tc4 + 1] = v.y;
            tile[tr + j * 16][tc4 + 2] = v.z;
            tile[tr + j * 16][tc4 + 3] = v.w;
        }
        __syncthreads();
        const int rr  = tid >> 2;
        const int ic0 = (tid & 3) * 16;
        const float s = S[r0 + rr];
        #pragma unroll
        for (int j = 0; j < 4; ++j) {
            bf16x4 o;
            #pragma unroll
            for (int q = 0; q < 4; ++q)
                o[q] = (bf16)(tile[ic0 + j * 4 + q][rr] * s);
            *(bf16x4*)&VsT[(size_t)(r0 + rr) * IN_DIM + i0 + ic0 + j * 4] = o;
        }
    }
}

__device__ __forceinline__ void gload16(const bf16* g, bf16* l)
{
    __builtin_amdgcn_global_load_lds(
        (const __attribute__((address_space(1))) void*)g,
        (__attribute__((address_space(3))) void*)l,
        16, 0, 0);
}

// ---------------------------------------------------------------------------
// gemm_bt_8p: C[M,N] = A[M,K]*B[N,K]^T, bf16 in, fp32 acc, CT out.
// 512 thr = 8 waves (2 wrow x 4 wcol), tile 256x256, BK=64, NT=K/64 tiles.
// LDS: [buf2][op2][half2][128x64] bf16 = 128 KiB, double-buffered.
// Swizzle (T2): logical (row,col) stored at colbyte ^ ((row&14)<<3); gload
// dest stays linear, the involution is applied to the GLOBAL source and to
// the LDS read address (rule #21). Per-16-lane read groups land 2-way (free).
// Pipeline (T3/T4): one half-tile staged per phase; tile t stages
//   p1:(t+1).B1 -> other buf, p3:(t+2).B0, p4:(t+2).A0+A1 -> current buf
// (each strictly after the closing barrier retiring that region's reads).
// Boundary s_waitcnt vmcnt(6) = 3 half-tiles in flight; never 0 mid-loop.
// ---------------------------------------------------------------------------
template <typename CT>
__global__ __launch_bounds__(512)
void gemm_bt_8p(const bf16* __restrict__ A, const bf16* __restrict__ B,
                CT* __restrict__ C, int M, int N, int K)
{
    __shared__ bf16 lds[2][2][2][8192];   // [buf][A/B][half][128*64]

    const int tid  = threadIdx.x;
    const int lane = tid & 63;
    const int wave = tid >> 6;       // 0..7
    const int wrow = wave >> 2;      // 0..1  (128-row half of C)
    const int wcol = wave & 3;       // 0..3  (64-col strip of C)
    const int n0 = blockIdx.x * 256;
    const int m0 = blockIdx.y * 256;
    const int NT = K >> 6;

    // --- staging constants: chunk c = wave*2+i covers rows wave*16+i*8+[0,8)
    // of a 128x64 half-tile; lane l -> row +(l>>3), col (l&7)*8 (pre-swizzled).
    const int srow8  = lane >> 3;
    const int colswz = ((lane & 7) * 8) ^ (((lane >> 4) & 1) * 8)
                                        ^ (((lane >> 5) & 1) * 16);

    // --- fragment-read constants: row hr = mi*16+fr, byteoff within half =
    // hr*128 + khalf*64 + kq2, XOR ((hr&14)<<3) = ((fr&14)<<3).
    const int fr   = lane & 15;
    const int kq2  = (lane >> 4) * 16;                    // bytes
    const int x45  = (fr & 6) << 3;
    const int x6   = (fr & 8) << 3;
    const int koffe[2] = { ((kq2 ^ x45) + (0  ^ x6)) >> 1,
                           ((kq2 ^ x45) + (64 ^ x6)) >> 1 };   // bf16 elts

    f32x4 acc[8][4];
    #pragma unroll
    for (int mi = 0; mi < 8; ++mi)
        #pragma unroll
        for (int ni = 0; ni < 4; ++ni)
            acc[mi][ni] = (f32x4){0.f, 0.f, 0.f, 0.f};

    auto STAGE = [&](const bf16* __restrict__ G, int g0, int tile, int op, int half) {
        bf16* dst = &lds[tile & 1][op][half][wave * 1024];
        #pragma unroll
        for (int i = 0; i < 2; ++i) {
            const int row = g0 + half * 128 + wave * 16 + i * 8 + srow8;
            const bf16* src = G + (size_t)row * K + tile * 64 + (colswz ^ (i * 32));
            gload16(src, dst + i * 512);
        }
    };

    // ---- prologue: tile0 all 4 half-tiles, tile1 A0,A1,B0 (B1 at t0.p1) ----
    STAGE(A, m0, 0, 0, 0); STAGE(A, m0, 0, 0, 1);
    STAGE(B, n0, 0, 1, 0); STAGE(B, n0, 0, 1, 1);
    if (NT > 1) {
        STAGE(A, m0, 1, 0, 0); STAGE(A, m0, 1, 0, 1); STAGE(B, n0, 1, 1, 0);
        asm volatile("s_waitcnt vmcnt(6)" ::: "memory");
    } else {
        asm volatile("s_waitcnt vmcnt(0)" ::: "memory");
    }
    __builtin_amdgcn_s_barrier();

    bf16x8 af[4][2], bv[4][2];

    for (int t = 0; t < NT; ++t) {
        const int cbuf = t & 1;
        const bf16* aB = &lds[cbuf][0][wrow][fr * 64];
        const bf16* bB = &lds[cbuf][1][wcol >> 1][(wcol & 1) * 4096 + fr * 64];

        // ================= phase 1: read A(mi0-3)+B(ni0-1), MFMA q1 ========
        #pragma unroll
        for (int q = 0; q < 4; ++q)
            #pragma unroll
            for (int h = 0; h < 2; ++h)
                af[q][h] = *(const bf16x8*)(aB + q * 1024 + koffe[h]);
        #pragma unroll
        for (int n = 0; n < 2; ++n)
            #pragma unroll
            for (int h = 0; h < 2; ++h)
                bv[n][h] = *(const bf16x8*)(bB + n * 1024 + koffe[h]);
        if (t + 1 < NT) STAGE(B, n0, t + 1, 1, 1);
        __builtin_amdgcn_s_barrier();
        asm volatile("s_waitcnt lgkmcnt(0)" ::: "memory");
        __builtin_amdgcn_sched_barrier(0);
        __builtin_amdgcn_s_setprio(1);
        #pragma unroll
        for (int q = 0; q < 4; ++q)
            #pragma unroll
            for (int n = 0; n < 2; ++n)
                #pragma unroll
                for (int h = 0; h < 2; ++h)
                    acc[q][n] = __builtin_amdgcn_mfma_f32_16x16x32_bf16(
                        af[q][h], bv[n][h], acc[q][n], 0, 0, 0);
        __builtin_amdgcn_s_setprio(0);
        __builtin_amdgcn_s_barrier();

        // ================= phase 2: read B(ni2-3), MFMA q2 =================
        #pragma unroll
        for (int n = 2; n < 4; ++n)
            #pragma unroll
            for (int h = 0; h < 2; ++h)
                bv[n][h] = *(const bf16x8*)(bB + n * 1024 + koffe[h]);
        __builtin_amdgcn_s_barrier();
        asm volatile("s_waitcnt lgkmcnt(0)" ::: "memory");
        __builtin_amdgcn_sched_barrier(0);
        __builtin_amdgcn_s_setprio(1);
        #pragma unroll
        for (int q = 0; q < 4; ++q)
            #pragma unroll
            for (int n = 2; n < 4; ++n)
                #pragma unroll
                for (int h = 0; h < 2; ++h)
                    acc[q][n] = __builtin_amdgcn_mfma_f32_16x16x32_bf16(
                        af[q][h], bv[n][h], acc[q][n], 0, 0, 0);
        __builtin_amdgcn_s_setprio(0);
        __builtin_amdgcn_s_barrier();

        // ================= phase 3: read A(mi4-7), MFMA q3 =================
        #pragma unroll
        for (int q = 0; q < 4; ++q)
            #pragma unroll
            for (int h = 0; h < 2; ++h)
                af[q][h] = *(const bf16x8*)(aB + (4 + q) * 1024 + koffe[h]);
        if (t + 2 < NT) STAGE(B, n0, t + 2, 1, 0);   // B reads retired at p2 barrier
        __builtin_amdgcn_s_barrier();
        asm volatile("s_waitcnt lgkmcnt(0)" ::: "memory");
        __builtin_amdgcn_sched_barrier(0);
        __builtin_amdgcn_s_setprio(1);
        #pragma unroll
        for (int q = 0; q < 4; ++q)
            #pragma unroll
            for (int n = 2; n < 4; ++n)
                #pragma unroll
                for (int h = 0; h < 2; ++h)
                    acc[4 + q][n] = __builtin_amdgcn_mfma_f32_16x16x32_bf16(
                        af[q][h], bv[n][h], acc[4 + q][n], 0, 0, 0);
        __builtin_amdgcn_s_setprio(0);
        __builtin_amdgcn_s_barrier();

        // ================= phase 4: MFMA q4, stage A(t+2), boundary vmcnt ==
        if (t + 2 < NT) {                             // A reads retired at p3 barrier
            STAGE(A, m0, t + 2, 0, 0);
            STAGE(A, m0, t + 2, 0, 1);
        }
        __builtin_amdgcn_s_barrier();
        asm volatile("s_waitcnt lgkmcnt(0)" ::: "memory");
        __builtin_amdgcn_sched_barrier(0);
        __builtin_amdgcn_s_setprio(1);
        #pragma unroll
        for (int q = 0; q < 4; ++q)
            #pragma unroll
            for (int n = 0; n < 2; ++n)
                #pragma unroll
                for (int h = 0; h < 2; ++h)
                    acc[4 + q][n] = __builtin_amdgcn_mfma_f32_16x16x32_bf16(
                        af[q][h], bv[n][h], acc[4 + q][n], 0, 0, 0);
        __builtin_amdgcn_s_setprio(0);
        if (t + 2 < NT)
            asm volatile("s_waitcnt vmcnt(6)" ::: "memory");  // 3 half-tiles in flight
        else if (t + 1 < NT)
            asm volatile("s_waitcnt vmcnt(0)" ::: "memory");  // drain for last tile
        __builtin_amdgcn_s_barrier();
    }

    // ---- epilogue: C/D layout col=lane&15, row=(lane>>4)*4+reg ----
    const int ccol  = n0 + wcol * 64 + fr;
    const int crow0 = m0 + wrow * 128 + (lane >> 4) * 4;
    #pragma unroll
    for (int mi = 0; mi < 8; ++mi)
        #pragma unroll
        for (int ni = 0; ni < 4; ++ni)
            #pragma unroll
            for (int r = 0; r < 4; ++r)
                C[(size_t)(crow0 + mi * 16 + r) * N + ccol + ni * 16] =
                    (CT)acc[mi][ni][r];
}

// ---------------------------------------------------------------------------
// Fallback GEMM1 (fp32 A, register staging, 128^2) — only if ws too small.
// ---------------------------------------------------------------------------
__global__ __launch_bounds__(256)
void gemm_bt_f32a(const float* __restrict__ A, const bf16* __restrict__ B,
                  bf16* __restrict__ C, int M, int N, int K)
{
    __shared__ bf16 As[128][40];
    __shared__ bf16 Bs[128][40];

    const int tid  = threadIdx.x;
    const int lane = tid & 63;
    const int wave = tid >> 6;
    const int wrow = wave >> 1;
    const int wcol = wave & 1;
    const int n0 = blockIdx.x * 128;
    const int m0 = blockIdx.y * 128;

    f32x4 acc[4][4];
    #pragma unroll
    for (int mi = 0; mi < 4; ++mi)
        #pragma unroll
        for (int ni = 0; ni < 4; ++ni)
            acc[mi][ni] = (f32x4){0.f, 0.f, 0.f, 0.f};

    const int fr = lane & 15;
    const int kq = (lane >> 4) * 8;

    for (int kk = 0; kk < K; kk += 32) {
        __syncthreads();
        #pragma unroll
        for (int i = 0; i < 4; ++i) {
            int c = tid + i * 256;
            int row = c >> 3, kc = (c & 7) * 4;
            float4 v = *(const float4*)&A[(size_t)(m0 + row) * K + kk + kc];
            bf16x4 o = { (bf16)v.x, (bf16)v.y, (bf16)v.z, (bf16)v.w };
            *(bf16x4*)&As[row][kc] = o;
        }
        #pragma unroll
        for (int i = 0; i < 2; ++i) {
            int c = tid + i * 256;
            int row = c >> 2, kc = (c & 3) * 8;
            *(bf16x8*)&Bs[row][kc] = *(const bf16x8*)&B[(size_t)(n0 + row) * K + kk + kc];
        }
        __syncthreads();

        bf16x8 af[4], bfg[4];
        #pragma unroll
        for (int i = 0; i < 4; ++i) {
            af[i]  = *(const bf16x8*)&As[wrow * 64 + i * 16 + fr][kq];
            bfg[i] = *(const bf16x8*)&Bs[wcol * 64 + i * 16 + fr][kq];
        }
        #pragma unroll
        for (int mi = 0; mi < 4; ++mi)
            #pragma unroll
            for (int ni = 0; ni < 4; ++ni)
                acc[mi][ni] = __builtin_amdgcn_mfma_f32_16x16x32_bf16(
                    af[mi], bfg[ni], acc[mi][ni], 0, 0, 0);
    }

    const int ccol  = n0 + wcol * 64 + fr;
    const int crow0 = m0 + wrow * 64 + (lane >> 4) * 4;
    #pragma unroll
    for (int mi = 0; mi < 4; ++mi)
        #pragma unroll
        for (int ni = 0; ni < 4; ++ni)
            #pragma unroll
            for (int r = 0; r < 4; ++r)
                C[(size_t)(crow0 + mi * 16 + r) * N + ccol + ni * 16] =
                    (bf16)acc[mi][ni][r];
}

// ---------------------------------------------------------------------------
extern "C" void kernel_launch(void* const* d_in, const int* in_sizes, int n_in,
                              void* d_out, int out_size, void* d_ws, size_t ws_size,
                              hipStream_t stream)
{
    const float* x = (const float*)d_in[0];
    const float* U = (const float*)d_in[1];
    const float* S = (const float*)d_in[2];
    const float* V = (const float*)d_in[3];
    float* out = (float*)d_out;

    const size_t SZ_XB  = (size_t)M_DIM * IN_DIM * 2;
    const size_t SZ_UB  = (size_t)OUT_DIM * RK_DIM * 2;
    const size_t SZ_VST = (size_t)RK_DIM * IN_DIM * 2;
    const size_t SZ_T   = (size_t)M_DIM * RK_DIM * 2;

    char* p = (char*)d_ws;
    const bool full = ws_size >= SZ_XB + SZ_UB + SZ_VST + SZ_T;
    bf16* xb = nullptr;
    if (full) { xb = (bf16*)p; p += SZ_XB; }
    bf16* Ub  = (bf16*)p; p += SZ_UB;
    bf16* VsT = (bf16*)p; p += SZ_VST;
    bf16* t   = (bf16*)p;

    const int xblocks = full ? 8192 : 0;
    prep_kernel<<<xblocks + 512 + 1024, 256, 0, stream>>>(
        x, U, S, V, full ? xb : Ub, Ub, VsT, xblocks);

    // GEMM1: t[M, RK] = xb[M, IN] * VsT[RK, IN]^T
    if (full)
        gemm_bt_8p<bf16><<<dim3(RK_DIM / 256, M_DIM / 256), 512, 0, stream>>>(
            xb, VsT, t, M_DIM, RK_DIM, IN_DIM);
    else
        gemm_bt_f32a<<<dim3(RK_DIM / 128, M_DIM / 128), 256, 0, stream>>>(
            x, VsT, t, M_DIM, RK_DIM, IN_DIM);

    // GEMM2: out[M, OUT] = t[M, RK] * Ub[OUT, RK]^T
    gemm_bt_8p<float><<<dim3(OUT_DIM / 256, M_DIM / 256), 512, 0, stream>>>(
        t, Ub, out, M_DIM, OUT_DIM, RK_DIM);
}

// Round 3
// 702.351 us; speedup vs baseline: 1.2403x; 1.0058x over previous
//
#include <hip/hip_runtime.h>

// FastHelgasonMLP: out = x @ (U diag(S) V^T)^T, factored:
//   t[16384,1024] = xb @ VsT^T ;  out[16384,4096] = t @ Ub^T
// R3: + bijective XCD-aware block remap in gemm_bt_8p so blocks sharing an
// A-panel are co-resident on one XCD (panel fetched once into that L2).
// 256x256 8-phase GEMM (T2 swizzle + T3/T4 counted-vmcnt + T5 setprio).

typedef __bf16 bf16;
typedef __bf16 bf16x4 __attribute__((ext_vector_type(4)));
typedef __bf16 bf16x8 __attribute__((ext_vector_type(8)));
typedef float  f32x4  __attribute__((ext_vector_type(4)));

#define M_DIM   16384
#define IN_DIM  4096
#define OUT_DIM 4096
#define RK_DIM  1024

// ---------------------------------------------------------------------------
// Prep (unchanged): cast x->bf16, U->bf16, build VsT[r][i] = V[i][r]*S[r].
// ---------------------------------------------------------------------------
__global__ __launch_bounds__(256)
void prep_kernel(const float* __restrict__ x, const float* __restrict__ U,
                 const float* __restrict__ S, const float* __restrict__ V,
                 bf16* __restrict__ xb, bf16* __restrict__ Ub,
                 bf16* __restrict__ VsT, int xblocks)
{
    __shared__ float tile[64][68];
    const int b = blockIdx.x;
    const int tid = threadIdx.x;

    if (b < xblocks) {
        const float4* xin = (const float4*)x;
        size_t base = (size_t)b * 2048 + tid;
        #pragma unroll
        for (int i = 0; i < 8; ++i) {
            float4 v = xin[base + (size_t)i * 256];
            bf16x4 o = { (bf16)v.x, (bf16)v.y, (bf16)v.z, (bf16)v.w };
            *(bf16x4*)&xb[(base + (size_t)i * 256) * 4] = o;
        }
    } else if (b < xblocks + 512) {
        const float4* uin = (const float4*)U;
        size_t base = (size_t)(b - xblocks) * 2048 + tid;
        #pragma unroll
        for (int i = 0; i < 8; ++i) {
            float4 v = uin[base + (size_t)i * 256];
            bf16x4 o = { (bf16)v.x, (bf16)v.y, (bf16)v.z, (bf16)v.w };
            *(bf16x4*)&Ub[(base + (size_t)i * 256) * 4] = o;
        }
    } else {
        const int vb   = b - (xblocks + 512);
        const int rblk = vb & 15;
        const int iblk = vb >> 4;
        const int r0 = rblk * 64, i0 = iblk * 64;

        const int tr  = tid >> 4;
        const int tc4 = (tid & 15) * 4;
        #pragma unroll
        for (int j = 0; j < 4; ++j) {
            float4 v = *(const float4*)&V[(size_t)(i0 + tr + j * 16) * RK_DIM + r0 + tc4];
            tile[tr + j * 16][tc4 + 0] = v.x;
            tile[tr + j * 16][tc4 + 1] = v.y;
            tile[tr + j * 16][tc4 + 2] = v.z;
            tile[tr + j * 16][tc4 + 3] = v.w;
        }
        __syncthreads();
        const int rr  = tid >> 2;
        const int ic0 = (tid & 3) * 16;
        const float s = S[r0 + rr];
        #pragma unroll
        for (int j = 0; j < 4; ++j) {
            bf16x4 o;
            #pragma unroll
            for (int q = 0; q < 4; ++q)
                o[q] = (bf16)(tile[ic0 + j * 4 + q][rr] * s);
            *(bf16x4*)&VsT[(size_t)(r0 + rr) * IN_DIM + i0 + ic0 + j * 4] = o;
        }
    }
}

__device__ __forceinline__ void gload16(const bf16* g, bf16* l)
{
    __builtin_amdgcn_global_load_lds(
        (const __attribute__((address_space(1))) void*)g,
        (__attribute__((address_space(3))) void*)l,
        16, 0, 0);
}

// ---------------------------------------------------------------------------
// gemm_bt_8p: C[M,N] = A[M,K]*B[N,K]^T, bf16 in, fp32 acc, CT out.
// 512 thr = 8 waves (2 wrow x 4 wcol), tile 256x256, BK=64, NT=K/64 tiles.
// LDS: [buf2][op2][half2][128x64] bf16 = 128 KiB, double-buffered.
// R3: XCD remap — hardware round-robins linear block id across 8 XCDs; we
// remap id -> work so each XCD's chunk of total/8 works is panel-major:
// all n-blocks of an A-panel run concurrently on ONE XCD -> A fetched once
// into that XCD's L2 (A-HBM traffic /= N/256).
// ---------------------------------------------------------------------------
template <typename CT>
__global__ __launch_bounds__(512)
void gemm_bt_8p(const bf16* __restrict__ A, const bf16* __restrict__ B,
                CT* __restrict__ C, int M, int N, int K)
{
    __shared__ bf16 lds[2][2][2][8192];   // [buf][A/B][half][128*64]

    const int tid  = threadIdx.x;
    const int lane = tid & 63;
    const int wave = tid >> 6;       // 0..7
    const int wrow = wave >> 2;      // 0..1  (128-row half of C)
    const int wcol = wave & 3;       // 0..3  (64-col strip of C)

    // ---- XCD-aware bijective remap (panel-co-location) ----
    int bx = blockIdx.x, by = blockIdx.y;
    {
        const int ncols = gridDim.x;
        const int total = ncols * gridDim.y;
        if ((total & 7) == 0) {
            const int h   = by * ncols + bx;     // hardware dispatch order
            const int per = total >> 3;          // works per XCD
            const int w   = (h & 7) * per + (h >> 3);
            by = w / ncols;
            bx = w - by * ncols;
        }
    }
    const int n0 = bx * 256;
    const int m0 = by * 256;
    const int NT = K >> 6;

    // --- staging constants: chunk c = wave*2+i covers rows wave*16+i*8+[0,8)
    // of a 128x64 half-tile; lane l -> row +(l>>3), col (l&7)*8 (pre-swizzled).
    const int srow8  = lane >> 3;
    const int colswz = ((lane & 7) * 8) ^ (((lane >> 4) & 1) * 8)
                                        ^ (((lane >> 5) & 1) * 16);

    // --- fragment-read constants: row hr = mi*16+fr, byteoff within half =
    // hr*128 + khalf*64 + kq2, XOR ((hr&14)<<3) = ((fr&14)<<3).
    const int fr   = lane & 15;
    const int kq2  = (lane >> 4) * 16;                    // bytes
    const int x45  = (fr & 6) << 3;
    const int x6   = (fr & 8) << 3;
    const int koffe[2] = { ((kq2 ^ x45) + (0  ^ x6)) >> 1,
                           ((kq2 ^ x45) + (64 ^ x6)) >> 1 };   // bf16 elts

    f32x4 acc[8][4];
    #pragma unroll
    for (int mi = 0; mi < 8; ++mi)
        #pragma unroll
        for (int ni = 0; ni < 4; ++ni)
            acc[mi][ni] = (f32x4){0.f, 0.f, 0.f, 0.f};

    auto STAGE = [&](const bf16* __restrict__ G, int g0, int tile, int op, int half) {
        bf16* dst = &lds[tile & 1][op][half][wave * 1024];
        #pragma unroll
        for (int i = 0; i < 2; ++i) {
            const int row = g0 + half * 128 + wave * 16 + i * 8 + srow8;
            const bf16* src = G + (size_t)row * K + tile * 64 + (colswz ^ (i * 32));
            gload16(src, dst + i * 512);
        }
    };

    // ---- prologue: tile0 all 4 half-tiles, tile1 A0,A1,B0 (B1 at t0.p1) ----
    STAGE(A, m0, 0, 0, 0); STAGE(A, m0, 0, 0, 1);
    STAGE(B, n0, 0, 1, 0); STAGE(B, n0, 0, 1, 1);
    if (NT > 1) {
        STAGE(A, m0, 1, 0, 0); STAGE(A, m0, 1, 0, 1); STAGE(B, n0, 1, 1, 0);
        asm volatile("s_waitcnt vmcnt(6)" ::: "memory");
    } else {
        asm volatile("s_waitcnt vmcnt(0)" ::: "memory");
    }
    __builtin_amdgcn_s_barrier();

    bf16x8 af[4][2], bv[4][2];

    for (int t = 0; t < NT; ++t) {
        const int cbuf = t & 1;
        const bf16* aB = &lds[cbuf][0][wrow][fr * 64];
        const bf16* bB = &lds[cbuf][1][wcol >> 1][(wcol & 1) * 4096 + fr * 64];

        // ================= phase 1: read A(mi0-3)+B(ni0-1), MFMA q1 ========
        #pragma unroll
        for (int q = 0; q < 4; ++q)
            #pragma unroll
            for (int h = 0; h < 2; ++h)
                af[q][h] = *(const bf16x8*)(aB + q * 1024 + koffe[h]);
        #pragma unroll
        for (int n = 0; n < 2; ++n)
            #pragma unroll
            for (int h = 0; h < 2; ++h)
                bv[n][h] = *(const bf16x8*)(bB + n * 1024 + koffe[h]);
        if (t + 1 < NT) STAGE(B, n0, t + 1, 1, 1);
        __builtin_amdgcn_s_barrier();
        asm volatile("s_waitcnt lgkmcnt(0)" ::: "memory");
        __builtin_amdgcn_sched_barrier(0);
        __builtin_amdgcn_s_setprio(1);
        #pragma unroll
        for (int q = 0; q < 4; ++q)
            #pragma unroll
            for (int n = 0; n < 2; ++n)
                #pragma unroll
                for (int h = 0; h < 2; ++h)
                    acc[q][n] = __builtin_amdgcn_mfma_f32_16x16x32_bf16(
                        af[q][h], bv[n][h], acc[q][n], 0, 0, 0);
        __builtin_amdgcn_s_setprio(0);
        __builtin_amdgcn_s_barrier();

        // ================= phase 2: read B(ni2-3), MFMA q2 =================
        #pragma unroll
        for (int n = 2; n < 4; ++n)
            #pragma unroll
            for (int h = 0; h < 2; ++h)
                bv[n][h] = *(const bf16x8*)(bB + n * 1024 + koffe[h]);
        __builtin_amdgcn_s_barrier();
        asm volatile("s_waitcnt lgkmcnt(0)" ::: "memory");
        __builtin_amdgcn_sched_barrier(0);
        __builtin_amdgcn_s_setprio(1);
        #pragma unroll
        for (int q = 0; q < 4; ++q)
            #pragma unroll
            for (int n = 2; n < 4; ++n)
                #pragma unroll
                for (int h = 0; h < 2; ++h)
                    acc[q][n] = __builtin_amdgcn_mfma_f32_16x16x32_bf16(
                        af[q][h], bv[n][h], acc[q][n], 0, 0, 0);
        __builtin_amdgcn_s_setprio(0);
        __builtin_amdgcn_s_barrier();

        // ================= phase 3: read A(mi4-7), MFMA q3 =================
        #pragma unroll
        for (int q = 0; q < 4; ++q)
            #pragma unroll
            for (int h = 0; h < 2; ++h)
                af[q][h] = *(const bf16x8*)(aB + (4 + q) * 1024 + koffe[h]);
        if (t + 2 < NT) STAGE(B, n0, t + 2, 1, 0);   // B reads retired at p2 barrier
        __builtin_amdgcn_s_barrier();
        asm volatile("s_waitcnt lgkmcnt(0)" ::: "memory");
        __builtin_amdgcn_sched_barrier(0);
        __builtin_amdgcn_s_setprio(1);
        #pragma unroll
        for (int q = 0; q < 4; ++q)
            #pragma unroll
            for (int n = 2; n < 4; ++n)
                #pragma unroll
                for (int h = 0; h < 2; ++h)
                    acc[4 + q][n] = __builtin_amdgcn_mfma_f32_16x16x32_bf16(
                        af[q][h], bv[n][h], acc[4 + q][n], 0, 0, 0);
        __builtin_amdgcn_s_setprio(0);
        __builtin_amdgcn_s_barrier();

        // ================= phase 4: MFMA q4, stage A(t+2), boundary vmcnt ==
        if (t + 2 < NT) {                             // A reads retired at p3 barrier
            STAGE(A, m0, t + 2, 0, 0);
            STAGE(A, m0, t + 2, 0, 1);
        }
        __builtin_amdgcn_s_barrier();
        asm volatile("s_waitcnt lgkmcnt(0)" ::: "memory");
        __builtin_amdgcn_sched_barrier(0);
        __builtin_amdgcn_s_setprio(1);
        #pragma unroll
        for (int q = 0; q < 4; ++q)
            #pragma unroll
            for (int n = 0; n < 2; ++n)
                #pragma unroll
                for (int h = 0; h < 2; ++h)
                    acc[4 + q][n] = __builtin_amdgcn_mfma_f32_16x16x32_bf16(
                        af[q][h], bv[n][h], acc[4 + q][n], 0, 0, 0);
        __builtin_amdgcn_s_setprio(0);
        if (t + 2 < NT)
            asm volatile("s_waitcnt vmcnt(6)" ::: "memory");  // 3 half-tiles in flight
        else if (t + 1 < NT)
            asm volatile("s_waitcnt vmcnt(0)" ::: "memory");  // drain for last tile
        __builtin_amdgcn_s_barrier();
    }

    // ---- epilogue: C/D layout col=lane&15, row=(lane>>4)*4+reg ----
    const int ccol  = n0 + wcol * 64 + fr;
    const int crow0 = m0 + wrow * 128 + (lane >> 4) * 4;
    #pragma unroll
    for (int mi = 0; mi < 8; ++mi)
        #pragma unroll
        for (int ni = 0; ni < 4; ++ni)
            #pragma unroll
            for (int r = 0; r < 4; ++r)
                C[(size_t)(crow0 + mi * 16 + r) * N + ccol + ni * 16] =
                    (CT)acc[mi][ni][r];
}

// ---------------------------------------------------------------------------
// Fallback GEMM1 (fp32 A, register staging, 128^2) — only if ws too small.
// ---------------------------------------------------------------------------
__global__ __launch_bounds__(256)
void gemm_bt_f32a(const float* __restrict__ A, const bf16* __restrict__ B,
                  bf16* __restrict__ C, int M, int N, int K)
{
    __shared__ bf16 As[128][40];
    __shared__ bf16 Bs[128][40];

    const int tid  = threadIdx.x;
    const int lane = tid & 63;
    const int wave = tid >> 6;
    const int wrow = wave >> 1;
    const int wcol = wave & 1;
    const int n0 = blockIdx.x * 128;
    const int m0 = blockIdx.y * 128;

    f32x4 acc[4][4];
    #pragma unroll
    for (int mi = 0; mi < 4; ++mi)
        #pragma unroll
        for (int ni = 0; ni < 4; ++ni)
            acc[mi][ni] = (f32x4){0.f, 0.f, 0.f, 0.f};

    const int fr = lane & 15;
    const int kq = (lane >> 4) * 8;

    for (int kk = 0; kk < K; kk += 32) {
        __syncthreads();
        #pragma unroll
        for (int i = 0; i < 4; ++i) {
            int c = tid + i * 256;
            int row = c >> 3, kc = (c & 7) * 4;
            float4 v = *(const float4*)&A[(size_t)(m0 + row) * K + kk + kc];
            bf16x4 o = { (bf16)v.x, (bf16)v.y, (bf16)v.z, (bf16)v.w };
            *(bf16x4*)&As[row][kc] = o;
        }
        #pragma unroll
        for (int i = 0; i < 2; ++i) {
            int c = tid + i * 256;
            int row = c >> 2, kc = (c & 3) * 8;
            *(bf16x8*)&Bs[row][kc] = *(const bf16x8*)&B[(size_t)(n0 + row) * K + kk + kc];
        }
        __syncthreads();

        bf16x8 af[4], bfg[4];
        #pragma unroll
        for (int i = 0; i < 4; ++i) {
            af[i]  = *(const bf16x8*)&As[wrow * 64 + i * 16 + fr][kq];
            bfg[i] = *(const bf16x8*)&Bs[wcol * 64 + i * 16 + fr][kq];
        }
        #pragma unroll
        for (int mi = 0; mi < 4; ++mi)
            #pragma unroll
            for (int ni = 0; ni < 4; ++ni)
                acc[mi][ni] = __builtin_amdgcn_mfma_f32_16x16x32_bf16(
                    af[mi], bfg[ni], acc[mi][ni], 0, 0, 0);
    }

    const int ccol  = n0 + wcol * 64 + fr;
    const int crow0 = m0 + wrow * 64 + (lane >> 4) * 4;
    #pragma unroll
    for (int mi = 0; mi < 4; ++mi)
        #pragma unroll
        for (int ni = 0; ni < 4; ++ni)
            #pragma unroll
            for (int r = 0; r < 4; ++r)
                C[(size_t)(crow0 + mi * 16 + r) * N + ccol + ni * 16] =
                    (bf16)acc[mi][ni][r];
}

// ---------------------------------------------------------------------------
extern "C" void kernel_launch(void* const* d_in, const int* in_sizes, int n_in,
                              void* d_out, int out_size, void* d_ws, size_t ws_size,
                              hipStream_t stream)
{
    const float* x = (const float*)d_in[0];
    const float* U = (const float*)d_in[1];
    const float* S = (const float*)d_in[2];
    const float* V = (const float*)d_in[3];
    float* out = (float*)d_out;

    const size_t SZ_XB  = (size_t)M_DIM * IN_DIM * 2;
    const size_t SZ_UB  = (size_t)OUT_DIM * RK_DIM * 2;
    const size_t SZ_VST = (size_t)RK_DIM * IN_DIM * 2;
    const size_t SZ_T   = (size_t)M_DIM * RK_DIM * 2;

    char* p = (char*)d_ws;
    const bool full = ws_size >= SZ_XB + SZ_UB + SZ_VST + SZ_T;
    bf16* xb = nullptr;
    if (full) { xb = (bf16*)p; p += SZ_XB; }
    bf16* Ub  = (bf16*)p; p += SZ_UB;
    bf16* VsT = (bf16*)p; p += SZ_VST;
    bf16* t   = (bf16*)p;

    const int xblocks = full ? 8192 : 0;
    prep_kernel<<<xblocks + 512 + 1024, 256, 0, stream>>>(
        x, U, S, V, full ? xb : Ub, Ub, VsT, xblocks);

    // GEMM1: t[M, RK] = xb[M, IN] * VsT[RK, IN]^T
    if (full)
        gemm_bt_8p<bf16><<<dim3(RK_DIM / 256, M_DIM / 256), 512, 0, stream>>>(
            xb, VsT, t, M_DIM, RK_DIM, IN_DIM);
    else
        gemm_bt_f32a<<<dim3(RK_DIM / 128, M_DIM / 128), 256, 0, stream>>>(
            x, VsT, t, M_DIM, RK_DIM, IN_DIM);

    // GEMM2: out[M, OUT] = t[M, RK] * Ub[OUT, RK]^T
    gemm_bt_8p<float><<<dim3(OUT_DIM / 256, M_DIM / 256), 512, 0, stream>>>(
        t, Ub, out, M_DIM, OUT_DIM, RK_DIM);
}